// Round 7
// baseline (227.320 us; speedup 1.0000x reference)
//
#include <hip/hip_runtime.h>
#include <math.h>

typedef unsigned short u16;
typedef __attribute__((ext_vector_type(8))) short bf16x8;
typedef __attribute__((ext_vector_type(4))) float f32x4;

#define MFMA16(a, b, c) __builtin_amdgcn_mfma_f32_16x16x32_bf16((a), (b), (c), 0, 0, 0)

#define B_ 2
#define S_ 2048
#define HID_ 2048
#define NH_ 16
#define NKV_ 4
#define HD_ 128
#define SCALE_ 0.08838834764831845f

static __device__ __forceinline__ u16 f2bf(float f) {
  unsigned u = __float_as_uint(f);
  u = (u + 0x7FFFu + ((u >> 16) & 1u)) >> 16;
  return (u16)u;
}

#define GLDS(src, dst)                                                        \
  __builtin_amdgcn_global_load_lds(                                           \
      (const __attribute__((address_space(1))) void*)(src),                   \
      (__attribute__((address_space(3))) void*)(dst), 16, 0, 0)

#define SCHED0 __builtin_amdgcn_sched_barrier(0)
#define BAR __builtin_amdgcn_s_barrier()

template <int N>
static __device__ __forceinline__ void waitv() {
  if constexpr (N == 0) asm volatile("s_waitcnt vmcnt(0)" ::: "memory");
  else if constexpr (N == 3) asm volatile("s_waitcnt vmcnt(3)" ::: "memory");
  else if constexpr (N == 4) asm volatile("s_waitcnt vmcnt(4)" ::: "memory");
  else if constexpr (N == 6) asm volatile("s_waitcnt vmcnt(6)" ::: "memory");
}

// Stage a tile (rows x (1<<CPRL) 16B-chunks per row) from global into LDS.
// 256-thread version (attn). LDS[r][bir] holds global[r][bir ^ ((r&7)<<4)].
template <int CPRL>
static __device__ __forceinline__ void stage_tile(const char* g0, long gstride,
                                                  char* lds) {
  int tid = threadIdx.x;
  int lane = tid & 63, wv = tid >> 6;
#pragma unroll
  for (int it = 0; it < 4; ++it) {
    int cb = wv * 256 + it * 64;  // wave-uniform chunk base
    int c = cb + lane;
    int r = c >> CPRL;
    int bir = (c & ((1 << CPRL) - 1)) << 4;
    int sbir = bir ^ ((r & 7) << 4);
    GLDS(g0 + (long)r * gstride + sbir, lds + cb * 16);
  }
}

// ---------------- prep kernels ----------------

__global__ __launch_bounds__(256) void conv_x(const float* __restrict__ x,
                                              u16* __restrict__ y) {
  size_t i = ((size_t)blockIdx.x * 256 + threadIdx.x) * 4;
  float4 v = *(const float4*)(x + i);
  ushort4 o = make_ushort4(f2bf(v.x), f2bf(v.y), f2bf(v.z), f2bf(v.w));
  *(ushort4*)(y + i) = o;
}

// dst[n*K + k] = bf16(src[k*N + n]);  grid: (N/32, K/32), block (32,8)
__global__ __launch_bounds__(256) void transpose_bf16(
    const float* __restrict__ src, u16* __restrict__ dst, int K, int N) {
  __shared__ float t[32][33];
  int n0 = blockIdx.x * 32, k0 = blockIdx.y * 32;
  int tx = threadIdx.x, ty = threadIdx.y;
#pragma unroll
  for (int i = 0; i < 4; ++i)
    t[ty + 8 * i][tx] = src[(size_t)(k0 + ty + 8 * i) * N + n0 + tx];
  __syncthreads();
#pragma unroll
  for (int i = 0; i < 4; ++i)
    dst[(size_t)(n0 + ty + 8 * i) * K + k0 + tx] = f2bf(t[tx][ty + 8 * i]);
}

__global__ __launch_bounds__(256) void prep_cstab(const int* __restrict__ pos,
                                                  float2* __restrict__ cs) {
  int i = blockIdx.x * 256 + threadIdx.x;  // [B*S * 64)
  int row = i >> 6, d = i & 63;
  float p = (float)pos[row];
  float inv = expf(-((float)(2 * d) * (1.0f / 128.0f)) * 13.815510557964274f);
  float a = p * inv;
  float s, c;
  sincosf(a, &s, &c);
  cs[i] = make_float2(c, s);
}

// ---------- 4-phase pipelined GEMM core (512 threads, 8 waves) ----------
// K-tile (BK=64) split into 4 phases = (K-half kk, N-half nh). Per phase:
//   issue ONE half-tile of tile t+1's staging (GLDS, linear dest)
//   counted vmcnt (never 0 except last tile) -> s_barrier -> ds_read only
//   this phase's fragments -> setprio(1) + MFMA cluster -> sched_barrier.
// LDS: [p][kh][rows][64B] K-half-major so half-tiles are GLDS-contiguous.
// Swizzle: 16B chunk ^ ((r>>1)&3) -> uniform 2-way bank aliasing (free).
// Wait arithmetic (stream order per tile: Ak0,Bk0,Ak1,Bk1; LA/LB loads per
// wave per half): entering phase0 of tile t, outstanding = t's 4 halves +
// t+1's Ak0 (just issued); need t's Ak0,Bk0 -> allow 2LA+LB. Phase2 needs
// t's Ak1,Bk1 -> allow t+1's Ak0+Bk0+Ak1 = 2LA+LB again. Last tile: no new
// issues -> allow LA+LB at p0, 0 at p2. Slot overwrites (t+1's half X into
// buf p^1) are >=2 barriers after X's last reader (tile t-1) — race-free.
template <int BM, int BN, int WM, int WN>
static __device__ __forceinline__ void gemm_core8(
    const u16* __restrict__ A, const u16* __restrict__ Bt, int K, int bm,
    int bn, char* Abuf, char* Bbuf,
    f32x4 (&acc)[(BM / WM) / 16][(BN / WN) / 16]) {
  constexpr int MF = (BM / WM) / 16;
  constexpr int NF = (BN / WN) / 16;
  constexpr int NH = NF / 2;
  constexpr int LA = BM / 128;  // GLDS per thread per A K-half
  constexpr int LB = BN / 128;
  constexpr int AH = BM * 64;  // bytes per A K-half buffer
  constexpr int BH = BN * 64;
  constexpr int WS = 2 * LA + LB;  // steady wait
  constexpr int WL = LA + LB;      // last-tile phase0 wait

  int tid = threadIdx.x, lane = tid & 63, wid = tid >> 6;
  int l16 = lane & 15, ln4 = lane >> 4;
  int wr = wid / WN, wc = wid % WN;

  const char* ga = (const char*)(A + (size_t)bm * BM * K);
  const char* gb = (const char*)(Bt + (size_t)bn * BN * K);
  long gs = (long)K * 2;
  int nkt = K / 64;

  auto stageA = [&](int t, int kh, int q) {
#pragma unroll
    for (int it = 0; it < LA; ++it) {
      int c = it * 512 + tid;
      int r = c >> 2;
      int g4 = (c & 3) ^ ((r >> 1) & 3);
      GLDS(ga + (long)r * gs + t * 128 + kh * 64 + g4 * 16,
           Abuf + (q * 2 + kh) * AH + c * 16);
    }
  };
  auto stageB = [&](int t, int kh, int q) {
#pragma unroll
    for (int it = 0; it < LB; ++it) {
      int c = it * 512 + tid;
      int r = c >> 2;
      int g4 = (c & 3) ^ ((r >> 1) & 3);
      GLDS(gb + (long)r * gs + t * 128 + kh * 64 + g4 * 16,
           Bbuf + (q * 2 + kh) * BH + c * 16);
    }
  };

  // prologue: tile 0 -> buffer 0 (order Ak0,Bk0,Ak1,Bk1 = wait stream order)
  stageA(0, 0, 0);
  stageB(0, 0, 0);
  stageA(0, 1, 0);
  stageB(0, 1, 0);

#pragma unroll 1
  for (int t = 0; t < nkt; ++t) {
    int p = t & 1, q = p ^ 1;
    bool nl = (t + 1 < nkt);
    const char* Ab = Abuf + p * 2 * AH;
    const char* Bb = Bbuf + p * 2 * BH;

    bf16x8 af[MF], bfr[NH];
    auto ldA = [&](int kh) {
#pragma unroll
      for (int m = 0; m < MF; ++m) {
        int r = wr * (BM / WM) + m * 16 + l16;
        af[m] = *(const bf16x8*)(Ab + kh * AH + r * 64 +
                                 16 * (ln4 ^ ((r >> 1) & 3)));
      }
    };
    auto ldB = [&](int kh, int nh) {
#pragma unroll
      for (int n = 0; n < NH; ++n) {
        int r = wc * (BN / WN) + (nh * NH + n) * 16 + l16;
        bfr[n] = *(const bf16x8*)(Bb + kh * BH + r * 64 +
                                  16 * (ln4 ^ ((r >> 1) & 3)));
      }
    };
    auto mm = [&](int nh) {
      __builtin_amdgcn_s_setprio(1);
#pragma unroll
      for (int m = 0; m < MF; ++m)
#pragma unroll
        for (int n = 0; n < NH; ++n)
          acc[m][nh * NH + n] = MFMA16(af[m], bfr[n], acc[m][nh * NH + n]);
      __builtin_amdgcn_s_setprio(0);
    };

    // ---- phase 0: kk0 x nh0 ----
    if (nl) stageA(t + 1, 0, q);
    if (nl) waitv<WS>(); else waitv<WL>();
    BAR; SCHED0;
    ldA(0);
    ldB(0, 0);
    mm(0);
    SCHED0;
    // ---- phase 1: kk0 x nh1 ----
    if (nl) stageB(t + 1, 0, q);
    BAR; SCHED0;
    ldB(0, 1);
    mm(1);
    SCHED0;
    // ---- phase 2: kk1 x nh0 ----
    if (nl) stageA(t + 1, 1, q);
    if (nl) waitv<WS>(); else waitv<0>();
    BAR; SCHED0;
    ldA(1);
    ldB(1, 0);
    mm(0);
    SCHED0;
    // ---- phase 3: kk1 x nh1 ----
    if (nl) stageB(t + 1, 1, q);
    BAR; SCHED0;
    ldB(1, 1);
    mm(1);
    SCHED0;
  }
}

// ---------------- GEMM1: QKV projection + bias + RoPE ----------------
// C[4096,3072] = Xb @ Wqkv_t^T. BM=BN=256, 8 waves as 4(M)x2(N): per-wave
// 64 rows x 128 cols -> each wave owns one 128-col head-block; RoPE pairs
// (d, d+64) = acc frags (bi, bi+4) are lane-local. Q pre-scaled by SCALE_.
__global__ __launch_bounds__(512) void gemm_qkv(
    const u16* __restrict__ Xb, const u16* __restrict__ Wt,
    const float* __restrict__ bq, const float* __restrict__ bk,
    const float* __restrict__ bv, const float2* __restrict__ cstab,
    u16* __restrict__ Qh, u16* __restrict__ Kh, u16* __restrict__ Vt) {
  __shared__ __align__(16) char Abuf[4 * 256 * 64];  // 64 KB [p][kh][256][64B]
  __shared__ __align__(16) char Bbuf[4 * 256 * 64];  // 64 KB
  int bid = blockIdx.x;
  int swz = (bid & 7) * 24 + (bid >> 3);  // XCD-contiguous chunks (192=8*24)
  int bm = swz / 12, bn = swz % 12;

  f32x4 acc[4][8] = {};
  gemm_core8<256, 256, 4, 2>(Xb, Wt, 2048, bm, bn, Abuf, Bbuf, acc);

  int tid = threadIdx.x, lane = tid & 63, wid = tid >> 6;
  int l16 = lane & 15, ln4 = lane >> 4;
  int wr = wid >> 1, wc = wid & 1;

  int cb = bn * 2 + wc;  // global 128-col head-block
  int region, hh;
  const float* bias;
  if (cb < 16) {
    region = 0; hh = cb; bias = bq;
  } else if (cb < 20) {
    region = 1; hh = cb - 16; bias = bk;
  } else {
    region = 2; hh = cb - 20; bias = bv;
  }
  float postscale = (region == 0) ? SCALE_ : 1.0f;

#pragma unroll
  for (int bi = 0; bi < 4; ++bi) {
    int dlo = bi * 16 + l16;  // 0..63
    float blo = bias[hh * 128 + dlo];
    float bhi = bias[hh * 128 + dlo + 64];
#pragma unroll
    for (int m = 0; m < 4; ++m) {
      int rbase = bm * 256 + wr * 64 + m * 16 + ln4 * 4;
      int bb = rbase >> 11;   // batch
      int s0 = rbase & 2047;  // seq
      if (region == 2) {
        // V: no rope; transposed store Vt[b][kvh][d][s], 4 consecutive s
        u16 pl[4], ph[4];
#pragma unroll
        for (int reg = 0; reg < 4; ++reg) {
          pl[reg] = f2bf(acc[m][bi][reg] + blo);
          ph[reg] = f2bf(acc[m][bi + 4][reg] + bhi);
        }
        size_t base = ((size_t)(bb * NKV_ + hh) * 128 + dlo) * 2048 + s0;
        *(ushort4*)(Vt + base) = make_ushort4(pl[0], pl[1], pl[2], pl[3]);
        *(ushort4*)(Vt + base + (size_t)64 * 2048) =
            make_ushort4(ph[0], ph[1], ph[2], ph[3]);
      } else {
#pragma unroll
        for (int reg = 0; reg < 4; ++reg) {
          int rg = rbase + reg;
          int s = rg & 2047;
          float vlo = acc[m][bi][reg] + blo;
          float vhi = acc[m][bi + 4][reg] + bhi;
          float2 cs = cstab[(size_t)rg * 64 + dlo];
          float nl = (vlo * cs.x - vhi * cs.y) * postscale;
          float nh = (vhi * cs.x + vlo * cs.y) * postscale;
          u16* dst = (region == 0)
                         ? Qh + ((size_t)(bb * NH_ + hh) * 2048 + s) * 128
                         : Kh + ((size_t)(bb * NKV_ + hh) * 2048 + s) * 128;
          dst[dlo] = f2bf(nl);
          dst[dlo + 64] = f2bf(nh);
        }
      }
    }
  }
}

// ---------------- attention: causal GQA flash ----------------
// 4 waves, single-buffered 40KB LDS (4 blocks/CU), XCD pinning (bid&7 ->
// (b,kvh): each XCD's L2 sees one 2MB K/V set), defer-max softmax.
__global__ __launch_bounds__(256) void attn(const u16* __restrict__ Qh,
                                            const u16* __restrict__ Kh,
                                            const u16* __restrict__ Vt,
                                            u16* __restrict__ ctx) {
  __shared__ __align__(16) char Ks[16384];   // [64 kv][128 d] swizzled
  __shared__ __align__(16) char Vs[16384];   // [128 d][64 kv] swizzled
  __shared__ __align__(16) char Ps[4][2048]; // per-wave [16 q][64 kv]
  int bid = blockIdx.x;
  int x = bid & 7;           // XCD group = (b, kvh)
  int b = x >> 2, kvh = x & 3;
  int i = bid >> 3;          // 0..127 within XCD group
  int hl = i & 3;            // head within kv group
  int qt = 31 - (i >> 2);    // heavy q-tiles first
  int h = kvh * 4 + hl;
  int q0 = qt * 64;
  int nt = qt + 1;

  int tid = threadIdx.x, lane = tid & 63, w = tid >> 6;
  int l16 = lane & 15, ln4 = lane >> 4;

  bf16x8 qf[4];
  const u16* qrow = Qh + ((size_t)(b * NH_ + h) * 2048 + q0 + w * 16 + l16) * 128;
#pragma unroll
  for (int kk = 0; kk < 4; ++kk)
    qf[kk] = *(const bf16x8*)(qrow + kk * 32 + ln4 * 8);

  f32x4 oacc[8] = {};
  float mrow[4], lsum[4];
#pragma unroll
  for (int r = 0; r < 4; ++r) {
    mrow[r] = -1e30f;
    lsum[r] = 0.0f;
  }

  const char* kbase = (const char*)(Kh + (size_t)(b * NKV_ + kvh) * 2048 * 128);
  const char* vbase = (const char*)(Vt + (size_t)(b * NKV_ + kvh) * 128 * 2048);

#pragma unroll 1
  for (int t = 0; t < nt; ++t) {
    __syncthreads();
    stage_tile<4>(kbase + (size_t)t * 64 * 256, 256, Ks);
    stage_tile<3>(vbase + (size_t)t * 128, 4096, Vs);
    __syncthreads();

    // S = Q K^T
    f32x4 sa[4] = {};
    __builtin_amdgcn_s_setprio(1);
#pragma unroll
    for (int kk = 0; kk < 4; ++kk) {
      bf16x8 kf[4];
#pragma unroll
      for (int n = 0; n < 4; ++n) {
        int r = n * 16 + l16;
        int off = r * 256 + ((kk * 64 + ln4 * 16) ^ ((r & 7) << 4));
        kf[n] = *(const bf16x8*)(Ks + off);
      }
#pragma unroll
      for (int n = 0; n < 4; ++n) sa[n] = MFMA16(qf[kk], kf[n], sa[n]);
    }
    __builtin_amdgcn_s_setprio(0);

    if (t == nt - 1) {
#pragma unroll
      for (int n = 0; n < 4; ++n)
#pragma unroll
        for (int reg = 0; reg < 4; ++reg)
          if (t * 64 + n * 16 + l16 > q0 + w * 16 + ln4 * 4 + reg)
            sa[n][reg] = -1e30f;
    }

    // shuffle-free defer-max test
    float tloc[4];
    int ok = 1;
#pragma unroll
    for (int reg = 0; reg < 4; ++reg) {
      tloc[reg] = fmaxf(fmaxf(sa[0][reg], sa[1][reg]),
                        fmaxf(sa[2][reg], sa[3][reg]));
      ok &= (tloc[reg] <= mrow[reg] + 8.0f);
    }
    if (!__all(ok)) {
#pragma unroll
      for (int reg = 0; reg < 4; ++reg) {
        float tm = tloc[reg];
#pragma unroll
        for (int mk = 1; mk < 16; mk <<= 1) tm = fmaxf(tm, __shfl_xor(tm, mk));
        float mnew = fmaxf(mrow[reg], tm);
        float scl = __expf(mrow[reg] - mnew);
        mrow[reg] = mnew;
        lsum[reg] *= scl;
#pragma unroll
        for (int nf = 0; nf < 8; ++nf) oacc[nf][reg] *= scl;
      }
    }

    // P = exp(S - m) -> wave-private LDS; per-lane lsum partials
#pragma unroll
    for (int reg = 0; reg < 4; ++reg) {
      int prow = ln4 * 4 + reg;
      float rs = 0.0f;
#pragma unroll
      for (int n = 0; n < 4; ++n) {
        float p = __expf(sa[n][reg] - mrow[reg]);
        rs += p;
        int off = prow * 128 + ((2 * (n * 16 + l16)) ^ ((prow & 7) << 4));
        *(u16*)(Ps[w] + off) = f2bf(p);
      }
      lsum[reg] += rs;
    }

    // O += P V
    __builtin_amdgcn_s_setprio(1);
#pragma unroll
    for (int kc = 0; kc < 2; ++kc) {
      int offa = l16 * 128 + ((kc * 64 + ln4 * 16) ^ ((l16 & 7) << 4));
      bf16x8 pa = *(const bf16x8*)(Ps[w] + offa);
#pragma unroll
      for (int nf = 0; nf < 8; ++nf) {
        int r = nf * 16 + l16;
        int off = r * 128 + ((kc * 64 + ln4 * 16) ^ ((r & 7) << 4));
        bf16x8 vf = *(const bf16x8*)(Vs + off);
        oacc[nf] = MFMA16(pa, vf, oacc[nf]);
      }
    }
    __builtin_amdgcn_s_setprio(0);
  }

  // epilogue
#pragma unroll
  for (int reg = 0; reg < 4; ++reg) {
#pragma unroll
    for (int mk = 1; mk < 16; mk <<= 1)
      lsum[reg] += __shfl_xor(lsum[reg], mk);
  }
#pragma unroll
  for (int reg = 0; reg < 4; ++reg) {
    float inv = 1.0f / lsum[reg];
    int s = q0 + w * 16 + ln4 * 4 + reg;
#pragma unroll
    for (int nf = 0; nf < 8; ++nf) {
      ctx[((size_t)(b * 2048 + s)) * 2048 + h * 128 + nf * 16 + l16] =
          f2bf(oacc[nf][reg] * inv);
    }
  }
}

// ---------------- GEMM2: out = ctx @ Wo (fp32 out) ----------------
// BM=128, BN=256, 8 waves as 2(M)x4(N): per-wave 64x64. Grid = 256 blocks.
__global__ __launch_bounds__(512) void gemm_out(const u16* __restrict__ Ab,
                                                const u16* __restrict__ Wt,
                                                float* __restrict__ out) {
  __shared__ __align__(16) char Abuf[4 * 128 * 64];  // 32 KB
  __shared__ __align__(16) char Bbuf[4 * 256 * 64];  // 64 KB
  int bid = blockIdx.x;
  int swz = (bid & 7) * 32 + (bid >> 3);  // XCD chunks (256=8*32)
  int bm = swz >> 3, bn = swz & 7;

  f32x4 acc[4][4] = {};
  gemm_core8<128, 256, 2, 4>(Ab, Wt, 2048, bm, bn, Abuf, Bbuf, acc);

  int tid = threadIdx.x, lane = tid & 63, wid = tid >> 6;
  int l16 = lane & 15, ln4 = lane >> 4;
  int wr = wid >> 2, wc = wid & 3;

#pragma unroll
  for (int m = 0; m < 4; ++m)
#pragma unroll
    for (int n = 0; n < 4; ++n)
#pragma unroll
      for (int reg = 0; reg < 4; ++reg) {
        int row = bm * 128 + wr * 64 + m * 16 + ln4 * 4 + reg;
        int col = bn * 256 + wc * 64 + n * 16 + l16;
        out[(size_t)row * 2048 + col] = acc[m][n][reg];
      }
}

// ---------------- launch ----------------

extern "C" void kernel_launch(void* const* d_in, const int* in_sizes, int n_in,
                              void* d_out, int out_size, void* d_ws,
                              size_t ws_size, hipStream_t stream) {
  const float* hid = (const float*)d_in[0];
  const int* pos = (const int*)d_in[1];
  const float* Wq = (const float*)d_in[2];
  const float* bq = (const float*)d_in[3];
  const float* Wk = (const float*)d_in[4];
  const float* bk = (const float*)d_in[5];
  const float* Wv = (const float*)d_in[6];
  const float* bv = (const float*)d_in[7];
  const float* Wo = (const float*)d_in[8];
  float* out = (float*)d_out;

  char* ws = (char*)d_ws;
  u16* Xb = (u16*)(ws + 0);                    // 16.78 MB  [4096][2048] bf16
  u16* Wqkvt = (u16*)(ws + 16777216UL);        // 12.58 MB  [3072][2048] bf16
  u16* Wot = (u16*)(ws + 29360128UL);          //  8.39 MB  [2048][2048] bf16
  u16* Qh = (u16*)(ws + 37748736UL);           // 16.78 MB  [B][NH][S][D]
  u16* Kh = (u16*)(ws + 54525952UL);           //  4.19 MB  [B][NKV][S][D]
  u16* Vt = (u16*)(ws + 58720256UL);           //  4.19 MB  [B][NKV][D][S]
  float2* cstab = (float2*)(ws + 62914560UL);  //  2.10 MB  [B*S][64]
  u16* ctx = Xb;  // alias: Xb dead after gemm_qkv

  conv_x<<<8192, 256, 0, stream>>>(hid, Xb);
  transpose_bf16<<<dim3(64, 64), dim3(32, 8), 0, stream>>>(Wq, Wqkvt, 2048,
                                                           2048);
  transpose_bf16<<<dim3(16, 64), dim3(32, 8), 0, stream>>>(
      Wk, Wqkvt + (size_t)2048 * 2048, 2048, 512);
  transpose_bf16<<<dim3(16, 64), dim3(32, 8), 0, stream>>>(
      Wv, Wqkvt + (size_t)2560 * 2048, 2048, 512);
  transpose_bf16<<<dim3(64, 64), dim3(32, 8), 0, stream>>>(Wo, Wot, 2048, 2048);
  prep_cstab<<<1024, 256, 0, stream>>>(pos, cstab);

  gemm_qkv<<<192, 512, 0, stream>>>(Xb, Wqkvt, bq, bk, bv, cstab, Qh, Kh, Vt);
  attn<<<1024, 256, 0, stream>>>(Qh, Kh, Vt, ctx);
  gemm_out<<<256, 512, 0, stream>>>(ctx, Wot, out);
}

// Round 8
// 220.966 us; speedup vs baseline: 1.0288x; 1.0288x over previous
//
#include <hip/hip_runtime.h>
#include <math.h>

typedef unsigned short u16;
typedef __attribute__((ext_vector_type(8))) short bf16x8;
typedef __attribute__((ext_vector_type(4))) float f32x4;

#define MFMA16(a, b, c) __builtin_amdgcn_mfma_f32_16x16x32_bf16((a), (b), (c), 0, 0, 0)

#define B_ 2
#define S_ 2048
#define HID_ 2048
#define NH_ 16
#define NKV_ 4
#define HD_ 128
#define SCALE_ 0.08838834764831845f

static __device__ __forceinline__ u16 f2bf(float f) {
  unsigned u = __float_as_uint(f);
  u = (u + 0x7FFFu + ((u >> 16) & 1u)) >> 16;
  return (u16)u;
}

#define GLDS(src, dst)                                                        \
  __builtin_amdgcn_global_load_lds(                                           \
      (const __attribute__((address_space(1))) void*)(src),                   \
      (__attribute__((address_space(3))) void*)(dst), 16, 0, 0)

#define BAR __builtin_amdgcn_s_barrier()
// rule #18: lgkmcnt(0) asm must be followed by sched_barrier(0)
#define LGKM0                                                                 \
  do {                                                                        \
    asm volatile("s_waitcnt lgkmcnt(0)" ::: "memory");                        \
    __builtin_amdgcn_sched_barrier(0);                                        \
  } while (0)

template <int N>
static __device__ __forceinline__ void waitv() {
  if constexpr (N == 0) asm volatile("s_waitcnt vmcnt(0)" ::: "memory");
  else if constexpr (N == 4) asm volatile("s_waitcnt vmcnt(4)" ::: "memory");
  else if constexpr (N == 6) asm volatile("s_waitcnt vmcnt(6)" ::: "memory");
}

// Stage a tile (rows x (1<<CPRL) 16B-chunks per row) from global into LDS.
// 256-thread version (attn). LDS[r][bir] holds global[r][bir ^ ((r&7)<<4)].
template <int CPRL>
static __device__ __forceinline__ void stage_tile(const char* g0, long gstride,
                                                  char* lds) {
  int tid = threadIdx.x;
  int lane = tid & 63, wv = tid >> 6;
#pragma unroll
  for (int it = 0; it < 4; ++it) {
    int cb = wv * 256 + it * 64;  // wave-uniform chunk base
    int c = cb + lane;
    int r = c >> CPRL;
    int bir = (c & ((1 << CPRL) - 1)) << 4;
    int sbir = bir ^ ((r & 7) << 4);
    GLDS(g0 + (long)r * gstride + sbir, lds + cb * 16);
  }
}

// ---------------- prep kernels ----------------

__global__ __launch_bounds__(256) void conv_x(const float* __restrict__ x,
                                              u16* __restrict__ y) {
  size_t i = ((size_t)blockIdx.x * 256 + threadIdx.x) * 4;
  float4 v = *(const float4*)(x + i);
  ushort4 o = make_ushort4(f2bf(v.x), f2bf(v.y), f2bf(v.z), f2bf(v.w));
  *(ushort4*)(y + i) = o;
}

// dst[n*K + k] = bf16(src[k*N + n]);  grid: (N/32, K/32), block (32,8)
__global__ __launch_bounds__(256) void transpose_bf16(
    const float* __restrict__ src, u16* __restrict__ dst, int K, int N) {
  __shared__ float t[32][33];
  int n0 = blockIdx.x * 32, k0 = blockIdx.y * 32;
  int tx = threadIdx.x, ty = threadIdx.y;
#pragma unroll
  for (int i = 0; i < 4; ++i)
    t[ty + 8 * i][tx] = src[(size_t)(k0 + ty + 8 * i) * N + n0 + tx];
  __syncthreads();
#pragma unroll
  for (int i = 0; i < 4; ++i)
    dst[(size_t)(n0 + ty + 8 * i) * K + k0 + tx] = f2bf(t[tx][ty + 8 * i]);
}

__global__ __launch_bounds__(256) void prep_cstab(const int* __restrict__ pos,
                                                  float2* __restrict__ cs) {
  int i = blockIdx.x * 256 + threadIdx.x;  // [B*S * 64)
  int row = i >> 6, d = i & 63;
  float p = (float)pos[row];
  float inv = expf(-((float)(2 * d) * (1.0f / 128.0f)) * 13.815510557964274f);
  float a = p * inv;
  float s, c;
  sincosf(a, &s, &c);
  cs[i] = make_float2(c, s);
}

// ---------- 8-phase pipelined GEMM core (512 threads, 8 waves) ----------
// m201 schedule. 2 K-tiles (BK=64) per iteration: phases p0-3 compute the 4
// output quadrants (q_r,q_c) of tile 2i from buf0, p4-7 tile 2i+1 from buf1.
// A-half h = rows with bit-LGA == h (quadrant-aligned); B-half likewise, so
// phase (q_r,q_c) reads exactly A-half q_r + B-half q_c. One half-tile is
// staged per phase into the region whose LAST READER was the previous phase
// (reads complete before that phase's trailing barrier via lgkmcnt(0) before
// its MFMAs) -> race-free. Stage stream per iter:
//   p0:(2i+1)Ah1  p1:(2i+1)Bh1  p2:(2i+2)Ah0  p3:(2i+2)Bh0
//   p4:(2i+2)Ah1  p5:(2i+2)Bh1  p6:(2i+3)Ah0  p7:(2i+3)Bh0
// vmcnt ONLY at p0/p4, allowing the newest 3 halves (= next tile's Ah0,Bh0,
// Ah1) outstanding: everything older (the tile about to be computed) landed.
// Final iteration's p4 drains to 0. Two barriers per phase.
// Swizzle: LDS[g][j] = global[R(g)][j ^ (g&7)] (16B chunks) -> 2-way bank
// aliasing on both staging and ds_read_b128 (free per m136).
template <int BM, int BN, int WM, int WN>
static __device__ __forceinline__ void gemm8(
    const u16* __restrict__ A, const u16* __restrict__ Bt, int K, int bm,
    int bn, char* __restrict__ Abuf, char* __restrict__ Bbuf,
    f32x4 (&acc)[(BM / WM) / 16][(BN / WN) / 16]) {
  constexpr int PWM = BM / WM, PWN = BN / WN;
  constexpr int QSA = PWM / 2, QSB = PWN / 2;   // quadrant sizes
  constexpr int MFR = QSA / 16, NFR = QSB / 16; // frags per quadrant
  constexpr int HA = BM / 2, HB = BN / 2;       // rows per half-buffer
  constexpr int LA = HA / 64, LB = HB / 64;     // GLDS per thread per half
  constexpr int WS = 2 * LA + LB;               // steady vmcnt
  constexpr int LGA = (QSA == 64) ? 6 : 5;
  constexpr int LGB = (QSB == 64) ? 6 : 5;

  int tid = threadIdx.x, lane = tid & 63, wid = tid >> 6;
  int l16 = lane & 15, ln4 = lane >> 4;
  int wr = wid / WN, wc = wid % WN;

  const char* ga = (const char*)(A + (size_t)bm * BM * K);
  const char* gb = (const char*)(Bt + (size_t)bn * BN * K);
  long gs = (long)K * 2;
  int nkt = K / 64;

  auto stA = [&](int t, int h, int p) {
    if (t >= nkt) return;
#pragma unroll
    for (int it = 0; it < LA; ++it) {
      int c = it * 512 + tid;
      int g = c >> 3, j = c & 7;
      int R = (g & (QSA - 1)) | ((g >> LGA) << (LGA + 1)) | (h << LGA);
      GLDS(ga + (long)R * gs + t * 128 + ((j ^ (g & 7)) << 4),
           Abuf + ((p * 2 + h) * HA) * 128 + c * 16);
    }
  };
  auto stB = [&](int t, int h, int p) {
    if (t >= nkt) return;
#pragma unroll
    for (int it = 0; it < LB; ++it) {
      int c = it * 512 + tid;
      int g = c >> 3, j = c & 7;
      int R = (g & (QSB - 1)) | ((g >> LGB) << (LGB + 1)) | (h << LGB);
      GLDS(gb + (long)R * gs + t * 128 + ((j ^ (g & 7)) << 4),
           Bbuf + ((p * 2 + h) * HB) * 128 + c * 16);
    }
  };

  bf16x8 fa[2][MFR], fb[2][NFR];
  auto LD = [&](int p, int qr, int qc) {
#pragma unroll
    for (int kk = 0; kk < 2; ++kk)
#pragma unroll
      for (int m = 0; m < MFR; ++m) {
        int g = wr * QSA + m * 16 + l16;
        fa[kk][m] = *(const bf16x8*)(Abuf + ((p * 2 + qr) * HA + g) * 128 +
                                     (((kk * 4 + ln4) ^ (g & 7)) << 4));
      }
#pragma unroll
    for (int kk = 0; kk < 2; ++kk)
#pragma unroll
      for (int n = 0; n < NFR; ++n) {
        int g = wc * QSB + n * 16 + l16;
        fb[kk][n] = *(const bf16x8*)(Bbuf + ((p * 2 + qc) * HB + g) * 128 +
                                     (((kk * 4 + ln4) ^ (g & 7)) << 4));
      }
  };
  auto MM = [&](int qr, int qc) {
    __builtin_amdgcn_s_setprio(1);
#pragma unroll
    for (int kk = 0; kk < 2; ++kk)
#pragma unroll
      for (int m = 0; m < MFR; ++m)
#pragma unroll
        for (int n = 0; n < NFR; ++n)
          acc[qr * MFR + m][qc * NFR + n] =
              MFMA16(fa[kk][m], fb[kk][n], acc[qr * MFR + m][qc * NFR + n]);
    __builtin_amdgcn_s_setprio(0);
  };

  // prologue: tile0 all 4 halves -> buf0; tile1 Ah0,Bh0 -> buf1
  stA(0, 0, 0); stB(0, 0, 0); stA(0, 1, 0); stB(0, 1, 0);
  stA(1, 0, 1); stB(1, 0, 1);

#pragma unroll 1
  for (int t2 = 0; t2 < nkt / 2; ++t2) {
    int ta = 2 * t2, tb = ta + 1;
    // p0
    stA(tb, 1, 1);
    waitv<WS>();
    BAR;
    LD(0, 0, 0); LGKM0; MM(0, 0);
    BAR;
    // p1
    LD(0, 0, 1); stB(tb, 1, 1); BAR; LGKM0; MM(0, 1); BAR;
    // p2
    LD(0, 1, 0); stA(ta + 2, 0, 0); BAR; LGKM0; MM(1, 0); BAR;
    // p3
    LD(0, 1, 1); stB(ta + 2, 0, 0); BAR; LGKM0; MM(1, 1); BAR;
    // p4
    stA(ta + 2, 1, 0);
    if (ta + 2 < nkt) waitv<WS>(); else waitv<0>();
    BAR;
    LD(1, 0, 0); LGKM0; MM(0, 0);
    BAR;
    // p5
    LD(1, 0, 1); stB(ta + 2, 1, 0); BAR; LGKM0; MM(0, 1); BAR;
    // p6
    LD(1, 1, 0); stA(tb + 2, 0, 1); BAR; LGKM0; MM(1, 0); BAR;
    // p7
    LD(1, 1, 1); stB(tb + 2, 0, 1); BAR; LGKM0; MM(1, 1); BAR;
  }
}

// ---------------- GEMM1: QKV projection + bias + RoPE ----------------
// C[4096,3072] = Xb @ Wqkv_t^T. BM=BN=256, waves 4(M)x2(N): per-wave 64 rows
// x 128 cols (one head-block) -> RoPE pairs (d,d+64) = acc frags (bi,bi+4)
// lane-local. Q pre-scaled by SCALE_.
__global__ __launch_bounds__(512, 2) void gemm_qkv(
    const u16* __restrict__ Xb, const u16* __restrict__ Wt,
    const float* __restrict__ bq, const float* __restrict__ bk,
    const float* __restrict__ bv, const float2* __restrict__ cstab,
    u16* __restrict__ Qh, u16* __restrict__ Kh, u16* __restrict__ Vt) {
  __shared__ __align__(16) char Abuf[4 * 128 * 128];  // 64 KB [p][h][128][128B]
  __shared__ __align__(16) char Bbuf[4 * 128 * 128];  // 64 KB
  int bid = blockIdx.x;
  int swz = (bid & 7) * 24 + (bid >> 3);  // XCD-contiguous chunks (192=8*24)
  int bm = swz / 12, bn = swz % 12;

  f32x4 acc[4][8] = {};
  gemm8<256, 256, 4, 2>(Xb, Wt, 2048, bm, bn, Abuf, Bbuf, acc);

  int tid = threadIdx.x, lane = tid & 63, wid = tid >> 6;
  int l16 = lane & 15, ln4 = lane >> 4;
  int wr = wid >> 1, wc = wid & 1;

  int cb = bn * 2 + wc;  // global 128-col head-block
  int region, hh;
  const float* bias;
  if (cb < 16) {
    region = 0; hh = cb; bias = bq;
  } else if (cb < 20) {
    region = 1; hh = cb - 16; bias = bk;
  } else {
    region = 2; hh = cb - 20; bias = bv;
  }
  float postscale = (region == 0) ? SCALE_ : 1.0f;

#pragma unroll
  for (int bi = 0; bi < 4; ++bi) {
    int dlo = bi * 16 + l16;  // 0..63
    float blo = bias[hh * 128 + dlo];
    float bhi = bias[hh * 128 + dlo + 64];
#pragma unroll
    for (int m = 0; m < 4; ++m) {
      int rbase = bm * 256 + wr * 64 + m * 16 + ln4 * 4;
      int bb = rbase >> 11;   // batch
      int s0 = rbase & 2047;  // seq
      if (region == 2) {
        // V: no rope; transposed store Vt[b][kvh][d][s], 4 consecutive s
        u16 pl[4], ph[4];
#pragma unroll
        for (int reg = 0; reg < 4; ++reg) {
          pl[reg] = f2bf(acc[m][bi][reg] + blo);
          ph[reg] = f2bf(acc[m][bi + 4][reg] + bhi);
        }
        size_t base = ((size_t)(bb * NKV_ + hh) * 128 + dlo) * 2048 + s0;
        *(ushort4*)(Vt + base) = make_ushort4(pl[0], pl[1], pl[2], pl[3]);
        *(ushort4*)(Vt + base + (size_t)64 * 2048) =
            make_ushort4(ph[0], ph[1], ph[2], ph[3]);
      } else {
#pragma unroll
        for (int reg = 0; reg < 4; ++reg) {
          int rg = rbase + reg;
          int s = rg & 2047;
          float vlo = acc[m][bi][reg] + blo;
          float vhi = acc[m][bi + 4][reg] + bhi;
          float2 cs = cstab[(size_t)rg * 64 + dlo];
          float nl = (vlo * cs.x - vhi * cs.y) * postscale;
          float nh = (vhi * cs.x + vlo * cs.y) * postscale;
          u16* dst = (region == 0)
                         ? Qh + ((size_t)(bb * NH_ + hh) * 2048 + s) * 128
                         : Kh + ((size_t)(bb * NKV_ + hh) * 2048 + s) * 128;
          dst[dlo] = f2bf(nl);
          dst[dlo + 64] = f2bf(nh);
        }
      }
    }
  }
}

// ---------------- attention: causal GQA flash ----------------
// 4 waves, single-buffered 40KB LDS, XCD pinning (bid&7 -> (b,kvh)), defer-
// max softmax. UNIFORM blocks: each block processes paired q-tiles (pr,
// 31-pr) sequentially -> exactly 33 kv-tiles per block (no causal tail).
__global__ __launch_bounds__(256) void attn(const u16* __restrict__ Qh,
                                            const u16* __restrict__ Kh,
                                            const u16* __restrict__ Vt,
                                            u16* __restrict__ ctx) {
  __shared__ __align__(16) char Ks[16384];   // [64 kv][128 d] swizzled
  __shared__ __align__(16) char Vs[16384];   // [128 d][64 kv] swizzled
  __shared__ __align__(16) char Ps[4][2048]; // per-wave [16 q][64 kv]
  int bid = blockIdx.x;
  int x = bid & 7;           // XCD group = (b, kvh)
  int b = x >> 2, kvh = x & 3;
  int i = bid >> 3;          // 0..63 within XCD group
  int hl = i & 3;            // head within kv group
  int pr = i >> 2;           // 0..15 pair index
  int h = kvh * 4 + hl;

  int tid = threadIdx.x, lane = tid & 63, w = tid >> 6;
  int l16 = lane & 15, ln4 = lane >> 4;

  const char* kbase = (const char*)(Kh + (size_t)(b * NKV_ + kvh) * 2048 * 128);
  const char* vbase = (const char*)(Vt + (size_t)(b * NKV_ + kvh) * 128 * 2048);

#pragma unroll 1
  for (int half = 0; half < 2; ++half) {
    int qt = half ? 31 - pr : pr;
    int q0 = qt * 64;
    int nt = qt + 1;

    bf16x8 qf[4];
    const u16* qrow =
        Qh + ((size_t)(b * NH_ + h) * 2048 + q0 + w * 16 + l16) * 128;
#pragma unroll
    for (int kk = 0; kk < 4; ++kk)
      qf[kk] = *(const bf16x8*)(qrow + kk * 32 + ln4 * 8);

    f32x4 oacc[8] = {};
    float mrow[4], lsum[4];
#pragma unroll
    for (int r = 0; r < 4; ++r) {
      mrow[r] = -1e30f;
      lsum[r] = 0.0f;
    }

#pragma unroll 1
    for (int t = 0; t < nt; ++t) {
      __syncthreads();
      stage_tile<4>(kbase + (size_t)t * 64 * 256, 256, Ks);
      stage_tile<3>(vbase + (size_t)t * 128, 4096, Vs);
      __syncthreads();

      // S = Q K^T
      f32x4 sa[4] = {};
      __builtin_amdgcn_s_setprio(1);
#pragma unroll
      for (int kk = 0; kk < 4; ++kk) {
        bf16x8 kf[4];
#pragma unroll
        for (int n = 0; n < 4; ++n) {
          int r = n * 16 + l16;
          int off = r * 256 + ((kk * 64 + ln4 * 16) ^ ((r & 7) << 4));
          kf[n] = *(const bf16x8*)(Ks + off);
        }
#pragma unroll
        for (int n = 0; n < 4; ++n) sa[n] = MFMA16(qf[kk], kf[n], sa[n]);
      }
      __builtin_amdgcn_s_setprio(0);

      if (t == nt - 1) {
#pragma unroll
        for (int n = 0; n < 4; ++n)
#pragma unroll
          for (int reg = 0; reg < 4; ++reg)
            if (t * 64 + n * 16 + l16 > q0 + w * 16 + ln4 * 4 + reg)
              sa[n][reg] = -1e30f;
      }

      // shuffle-free defer-max test
      float tloc[4];
      int ok = 1;
#pragma unroll
      for (int reg = 0; reg < 4; ++reg) {
        tloc[reg] = fmaxf(fmaxf(sa[0][reg], sa[1][reg]),
                          fmaxf(sa[2][reg], sa[3][reg]));
        ok &= (tloc[reg] <= mrow[reg] + 8.0f);
      }
      if (!__all(ok)) {
#pragma unroll
        for (int reg = 0; reg < 4; ++reg) {
          float tm = tloc[reg];
#pragma unroll
          for (int mk = 1; mk < 16; mk <<= 1)
            tm = fmaxf(tm, __shfl_xor(tm, mk));
          float mnew = fmaxf(mrow[reg], tm);
          float scl = __expf(mrow[reg] - mnew);
          mrow[reg] = mnew;
          lsum[reg] *= scl;
#pragma unroll
          for (int nf = 0; nf < 8; ++nf) oacc[nf][reg] *= scl;
        }
      }

      // P = exp(S - m) -> wave-private LDS; per-lane lsum partials
#pragma unroll
      for (int reg = 0; reg < 4; ++reg) {
        int prow = ln4 * 4 + reg;
        float rs = 0.0f;
#pragma unroll
        for (int n = 0; n < 4; ++n) {
          float p = __expf(sa[n][reg] - mrow[reg]);
          rs += p;
          int off = prow * 128 + ((2 * (n * 16 + l16)) ^ ((prow & 7) << 4));
          *(u16*)(Ps[w] + off) = f2bf(p);
        }
        lsum[reg] += rs;
      }

      // O += P V
      __builtin_amdgcn_s_setprio(1);
#pragma unroll
      for (int kc = 0; kc < 2; ++kc) {
        int offa = l16 * 128 + ((kc * 64 + ln4 * 16) ^ ((l16 & 7) << 4));
        bf16x8 pa = *(const bf16x8*)(Ps[w] + offa);
#pragma unroll
        for (int nf = 0; nf < 8; ++nf) {
          int r = nf * 16 + l16;
          int off = r * 128 + ((kc * 64 + ln4 * 16) ^ ((r & 7) << 4));
          bf16x8 vf = *(const bf16x8*)(Vs + off);
          oacc[nf] = MFMA16(pa, vf, oacc[nf]);
        }
      }
      __builtin_amdgcn_s_setprio(0);
    }

    // epilogue: reduce per-lane lsum partials, write ctx
#pragma unroll
    for (int reg = 0; reg < 4; ++reg) {
#pragma unroll
      for (int mk = 1; mk < 16; mk <<= 1)
        lsum[reg] += __shfl_xor(lsum[reg], mk);
    }
#pragma unroll
    for (int reg = 0; reg < 4; ++reg) {
      float inv = 1.0f / lsum[reg];
      int s = q0 + w * 16 + ln4 * 4 + reg;
#pragma unroll
      for (int nf = 0; nf < 8; ++nf) {
        ctx[((size_t)(b * 2048 + s)) * 2048 + h * 128 + nf * 16 + l16] =
            f2bf(oacc[nf][reg] * inv);
      }
    }
  }
}

// ---------------- GEMM2: out = ctx @ Wo (fp32 out) ----------------
// BM=128, BN=256, waves 2(M)x4(N): per-wave 64x64. Grid = 256 blocks.
__global__ __launch_bounds__(512, 2) void gemm_out(const u16* __restrict__ Ab,
                                                   const u16* __restrict__ Wt,
                                                   float* __restrict__ out) {
  __shared__ __align__(16) char Abuf[4 * 64 * 128];   // 32 KB
  __shared__ __align__(16) char Bbuf[4 * 128 * 128];  // 64 KB
  int bid = blockIdx.x;
  int swz = (bid & 7) * 32 + (bid >> 3);  // XCD chunks (256=8*32)
  int bm = swz >> 3, bn = swz & 7;

  f32x4 acc[4][4] = {};
  gemm8<128, 256, 2, 4>(Ab, Wt, 2048, bm, bn, Abuf, Bbuf, acc);

  int tid = threadIdx.x, lane = tid & 63, wid = tid >> 6;
  int l16 = lane & 15, ln4 = lane >> 4;
  int wr = wid >> 2, wc = wid & 3;

#pragma unroll
  for (int m = 0; m < 4; ++m)
#pragma unroll
    for (int n = 0; n < 4; ++n)
#pragma unroll
      for (int reg = 0; reg < 4; ++reg) {
        int row = bm * 128 + wr * 64 + m * 16 + ln4 * 4 + reg;
        int col = bn * 256 + wc * 64 + n * 16 + l16;
        out[(size_t)row * 2048 + col] = acc[m][n][reg];
      }
}

// ---------------- launch ----------------

extern "C" void kernel_launch(void* const* d_in, const int* in_sizes, int n_in,
                              void* d_out, int out_size, void* d_ws,
                              size_t ws_size, hipStream_t stream) {
  const float* hid = (const float*)d_in[0];
  const int* pos = (const int*)d_in[1];
  const float* Wq = (const float*)d_in[2];
  const float* bq = (const float*)d_in[3];
  const float* Wk = (const float*)d_in[4];
  const float* bk = (const float*)d_in[5];
  const float* Wv = (const float*)d_in[6];
  const float* bv = (const float*)d_in[7];
  const float* Wo = (const float*)d_in[8];
  float* out = (float*)d_out;

  char* ws = (char*)d_ws;
  u16* Xb = (u16*)(ws + 0);                    // 16.78 MB  [4096][2048] bf16
  u16* Wqkvt = (u16*)(ws + 16777216UL);        // 12.58 MB  [3072][2048] bf16
  u16* Wot = (u16*)(ws + 29360128UL);          //  8.39 MB  [2048][2048] bf16
  u16* Qh = (u16*)(ws + 37748736UL);           // 16.78 MB  [B][NH][S][D]
  u16* Kh = (u16*)(ws + 54525952UL);           //  4.19 MB  [B][NKV][S][D]
  u16* Vt = (u16*)(ws + 58720256UL);           //  4.19 MB  [B][NKV][D][S]
  float2* cstab = (float2*)(ws + 62914560UL);  //  2.10 MB  [B*S][64]
  u16* ctx = Xb;  // alias: Xb dead after gemm_qkv

  conv_x<<<8192, 256, 0, stream>>>(hid, Xb);
  transpose_bf16<<<dim3(64, 64), dim3(32, 8), 0, stream>>>(Wq, Wqkvt, 2048,
                                                           2048);
  transpose_bf16<<<dim3(16, 64), dim3(32, 8), 0, stream>>>(
      Wk, Wqkvt + (size_t)2048 * 2048, 2048, 512);
  transpose_bf16<<<dim3(16, 64), dim3(32, 8), 0, stream>>>(
      Wv, Wqkvt + (size_t)2560 * 2048, 2048, 512);
  transpose_bf16<<<dim3(64, 64), dim3(32, 8), 0, stream>>>(Wo, Wot, 2048, 2048);
  prep_cstab<<<1024, 256, 0, stream>>>(pos, cstab);

  gemm_qkv<<<192, 512, 0, stream>>>(Xb, Wqkvt, bq, bk, bv, cstab, Qh, Kh, Vt);
  attn<<<512, 256, 0, stream>>>(Qh, Kh, Vt, ctx);
  gemm_out<<<256, 512, 0, stream>>>(ctx, Wot, out);
}